// Round 1
// baseline (125.128 us; speedup 1.0000x reference)
//
#include <hip/hip_runtime.h>
#include <hip/hip_cooperative_groups.h>
#include <math.h>

// BoundaryLoss: out = mean |sigmoid(logits) - gt| * EDT_bg(gt)
// dist==0 exactly at gt==1  ->  |p-t|*dist == p*dist: targets only feed the
// fg bitmask.
// FUSED single cooperative kernel:
//   Phase A0: prefetch this block's logits stripe -> LDS (overlaps A1+sync)
//   Phase A1: pack 192 mask words/block (global coverage) -> workspace
//   grid.sync()
//   Phase B: per 16-col stripe: bitmask -> LDS, clz/ffs exact row distances,
//            early-exit exact vertical envelope, fused sigmoid*dist reduce.
// Fallback: original two-kernel path if cooperative launch unavailable.

#define BB 16
#define HH 384
#define WW 384
#define WPR 12                 // u32 words per row
#define WPRP 13                // padded LDS stride (coprime 32: conflict-free)
#define SW 16                  // stripe width
#define LSP 20                 // padded logits LDS stride (floats): banks spread
#define NBLK (WW / SW)         // 24
#define THREADS 512
#define NBLOCKS (BB * NBLK)    // 384
#define WPB ((BB * HH * WPR) / NBLOCKS)  // 192 mask words per block
#define PTHREADS 256
#define BIGD 768

namespace cg = cooperative_groups;

__global__ __launch_bounds__(THREADS, 4) void fused_kernel(
    const float* __restrict__ logits, const int* __restrict__ gt,
    unsigned* __restrict__ mask, float* __restrict__ out) {
  const int blk = blockIdx.x;
  const int b = blk / NBLK;
  const int j0 = (blk % NBLK) * SW;
  const float* __restrict__ lg = logits + b * HH * WW;

  __shared__ unsigned m_s[HH * WPRP];       // 19968 B
  __shared__ unsigned short g_s[HH * SW];   // 12288 B
  __shared__ float l_s[HH * LSP];           // 30720 B   (total 62976 B)

  // ---- Phase A0: logits stripe -> LDS (independent of mask; hides HBM) ----
  for (int s = threadIdx.x; s < HH * (SW / 4); s += THREADS) {  // 1536
    const int i = s >> 2;
    const int jj = (s & 3) * 4;
    *(float4*)(l_s + i * LSP + jj) = *(const float4*)(lg + i * WW + j0 + jj);
  }

  // ---- Phase A1: pack fg bitmask, 1 word (32 px) per thread ----
  if (threadIdx.x < WPB) {
    const int wi = blk * WPB + threadIdx.x;   // linear word index == layout
    const int4* __restrict__ g4 = (const int4*)(gt + (size_t)wi * 32);
    unsigned word = 0;
#pragma unroll
    for (int k = 0; k < 8; ++k) {
      const int4 v = g4[k];
      word |= ((unsigned)(v.x != 0)) << (k * 4);
      word |= ((unsigned)(v.y != 0)) << (k * 4 + 1);
      word |= ((unsigned)(v.z != 0)) << (k * 4 + 2);
      word |= ((unsigned)(v.w != 0)) << (k * 4 + 3);
    }
    mask[wi] = word;
  }
  if (blk == 0 && threadIdx.x == THREADS - 1) out[0] = 0.0f;

  cg::this_grid().sync();   // mask complete + out zeroed, device-visible

  // ---- stage fg bitmask slab: uint4 loads, scalar LDS writes (padded) ----
  const uint4* __restrict__ gm4 = (const uint4*)(mask + b * HH * WPR);
  for (int s = threadIdx.x; s < HH * WPR / 4; s += THREADS) {  // 1152
    const uint4 v = gm4[s];
    const int row = s / 3;
    const int w0 = (s - row * 3) * 4;
    unsigned* dst = m_s + row * WPRP + w0;
    dst[0] = v.x; dst[1] = v.y; dst[2] = v.z; dst[3] = v.w;
  }
  __syncthreads();

  // ---- Phase 1: exact nearest-fg row distance, 4 cols/thread ----
  for (int s = threadIdx.x; s < HH * (SW / 4); s += THREADS) {  // 1536
    const int i = s >> 2;
    const int jj = (s & 3) * 4;
    const int j = j0 + jj;                  // multiple of 4: 4 bits in one word
    const unsigned* __restrict__ mr = m_s + i * WPRP;
    const int w = j >> 5;
    const int bpos = j & 31;                // 0,4,...,28
    const unsigned cur = mr[w];

    int jL = -0x40000;
    if ((cur & (0xFFFFFFFFu >> (31 - bpos))) == 0u) {
      for (int ww = w - 1; ww >= 0; --ww) {
        const unsigned x = mr[ww];
        if (x) { jL = ww * 32 + 31 - __clz(x); break; }
      }
    }
    int jR = 0x40000;
    if ((cur & (0xFFFFFFFFu << (bpos + 3))) == 0u) {
      for (int ww = w + 1; ww < WPR; ++ww) {
        const unsigned x = mr[ww];
        if (x) { jR = ww * 32 + __ffs(x) - 1; break; }
      }
    }
    unsigned short g4[4];
#pragma unroll
    for (int c = 0; c < 4; ++c) {
      const int bc = bpos + c;
      const int jc = j + c;
      const unsigned lm = cur & (0xFFFFFFFFu >> (31 - bc));
      const unsigned rm = cur & (0xFFFFFFFFu << bc);
      const int dl = lm ? (bc - (31 - __clz(lm))) : (jc - jL);
      const int dr = rm ? ((__ffs(rm) - 1) - bc) : (jR - jc);
      g4[c] = (unsigned short)min(min(dl, dr), BIGD);
    }
    ushort4 gv; gv.x = g4[0]; gv.y = g4[1]; gv.z = g4[2]; gv.w = g4[3];
    *(ushort4*)(g_s + i * SW + jj) = gv;
  }
  __syncthreads();

  // ---- Phase 2: exact vertical envelope (early exit r*r >= best) + loss ----
  float acc = 0.0f;
  for (int s = threadIdx.x; s < HH * (SW / 4); s += THREADS) {
    const int i = s >> 2;
    const int jj = (s & 3) * 4;
    const ushort4 gv = *(const ushort4*)(g_s + i * SW + jj);
    const float4 x4 = *(const float4*)(l_s + i * LSP + jj);
    const int gg[4] = {gv.x, gv.y, gv.z, gv.w};
    const float xs[4] = {x4.x, x4.y, x4.z, x4.w};
#pragma unroll
    for (int c = 0; c < 4; ++c) {
      int best = gg[c] * gg[c];
      for (int r = 1; r * r < best; ++r) {
        const int im = i - r, ip = i + r;
        if (im >= 0) { const int v = g_s[im * SW + jj + c]; best = min(best, r * r + v * v); }
        if (ip < HH) { const int v = g_s[ip * SW + jj + c]; best = min(best, r * r + v * v); }
      }
      const float dist = __builtin_amdgcn_sqrtf((float)best);     // rel ~1e-7
      const float p = __builtin_amdgcn_rcpf(1.0f + __expf(-xs[c])); // rel ~2.5e-7
      acc += p * dist;                        // == |p-t|*dist (dist=0 at fg)
    }
  }

  // ---- Block reduction -> one fire-and-forget atomic per block ----
  __shared__ float red[THREADS / 64];
  for (int off = 32; off > 0; off >>= 1) acc += __shfl_down(acc, off, 64);
  const int lane = threadIdx.x & 63;
  const int wid = threadIdx.x >> 6;
  if (lane == 0) red[wid] = acc;
  __syncthreads();
  if (threadIdx.x == 0) {
    float ssum = 0.0f;
    for (int w = 0; w < THREADS / 64; ++w) ssum += red[w];
    atomicAdd(out, ssum * (1.0f / (float)(BB * HH * WW)));
  }
}

// ---------------- Fallback path (original two-kernel structure) ------------

__global__ __launch_bounds__(PTHREADS) void pack_kernel(
    const int* __restrict__ gt, unsigned* __restrict__ mask,
    float* __restrict__ out) {
  __shared__ unsigned char s_byte[PTHREADS];
  const int base = blockIdx.x * PTHREADS * 8;        // 2048 px per block
  const int4* __restrict__ g4 = (const int4*)(gt + base);
  const int4 a = g4[threadIdx.x * 2];
  const int4 b = g4[threadIdx.x * 2 + 1];
  unsigned byte = (a.x != 0) | ((a.y != 0) << 1) | ((a.z != 0) << 2) |
                  ((a.w != 0) << 3) | ((b.x != 0) << 4) | ((b.y != 0) << 5) |
                  ((b.z != 0) << 6) | ((b.w != 0) << 7);
  s_byte[threadIdx.x] = (unsigned char)byte;
  __syncthreads();
  if (threadIdx.x < PTHREADS / 4) {                  // 64 word stores
    mask[(base >> 5) + threadIdx.x] = *(const unsigned*)(s_byte + threadIdx.x * 4);
  }
  if (blockIdx.x == 0 && threadIdx.x == 0) out[0] = 0.0f;
}

__global__ __launch_bounds__(THREADS) void boundary_loss_kernel(
    const float* __restrict__ logits, const unsigned* __restrict__ mask,
    float* __restrict__ out) {
  const int blk = blockIdx.x;
  const int b = blk / NBLK;
  const int j0 = (blk % NBLK) * SW;
  const float* __restrict__ lg = logits + b * HH * WW;

  __shared__ unsigned m_s[HH * WPRP];
  __shared__ unsigned short g_s[HH * SW];

  const uint4* __restrict__ gm4 = (const uint4*)(mask + b * HH * WPR);
  for (int s = threadIdx.x; s < HH * WPR / 4; s += THREADS) {
    const uint4 v = gm4[s];
    const int row = s / 3;
    const int w0 = (s - row * 3) * 4;
    unsigned* dst = m_s + row * WPRP + w0;
    dst[0] = v.x; dst[1] = v.y; dst[2] = v.z; dst[3] = v.w;
  }
  __syncthreads();

  for (int s = threadIdx.x; s < HH * (SW / 4); s += THREADS) {
    const int i = s >> 2;
    const int jj = (s & 3) * 4;
    const int j = j0 + jj;
    const unsigned* __restrict__ mr = m_s + i * WPRP;
    const int w = j >> 5;
    const int bpos = j & 31;
    const unsigned cur = mr[w];

    int jL = -0x40000;
    if ((cur & (0xFFFFFFFFu >> (31 - bpos))) == 0u) {
      for (int ww = w - 1; ww >= 0; --ww) {
        const unsigned x = mr[ww];
        if (x) { jL = ww * 32 + 31 - __clz(x); break; }
      }
    }
    int jR = 0x40000;
    if ((cur & (0xFFFFFFFFu << (bpos + 3))) == 0u) {
      for (int ww = w + 1; ww < WPR; ++ww) {
        const unsigned x = mr[ww];
        if (x) { jR = ww * 32 + __ffs(x) - 1; break; }
      }
    }
    unsigned short g4[4];
#pragma unroll
    for (int c = 0; c < 4; ++c) {
      const int bc = bpos + c;
      const int jc = j + c;
      const unsigned lm = cur & (0xFFFFFFFFu >> (31 - bc));
      const unsigned rm = cur & (0xFFFFFFFFu << bc);
      const int dl = lm ? (bc - (31 - __clz(lm))) : (jc - jL);
      const int dr = rm ? ((__ffs(rm) - 1) - bc) : (jR - jc);
      g4[c] = (unsigned short)min(min(dl, dr), BIGD);
    }
    ushort4 gv; gv.x = g4[0]; gv.y = g4[1]; gv.z = g4[2]; gv.w = g4[3];
    *(ushort4*)(g_s + i * SW + jj) = gv;
  }
  __syncthreads();

  float acc = 0.0f;
  for (int s = threadIdx.x; s < HH * (SW / 4); s += THREADS) {
    const int i = s >> 2;
    const int jj = (s & 3) * 4;
    const ushort4 gv = *(const ushort4*)(g_s + i * SW + jj);
    const float4 x4 = *(const float4*)(lg + i * WW + j0 + jj);
    const int gg[4] = {gv.x, gv.y, gv.z, gv.w};
    const float xs[4] = {x4.x, x4.y, x4.z, x4.w};
#pragma unroll
    for (int c = 0; c < 4; ++c) {
      int best = gg[c] * gg[c];
      for (int r = 1; r * r < best; ++r) {
        const int im = i - r, ip = i + r;
        if (im >= 0) { const int v = g_s[im * SW + jj + c]; best = min(best, r * r + v * v); }
        if (ip < HH) { const int v = g_s[ip * SW + jj + c]; best = min(best, r * r + v * v); }
      }
      const float dist = __builtin_amdgcn_sqrtf((float)best);
      const float p = __builtin_amdgcn_rcpf(1.0f + __expf(-xs[c]));
      acc += p * dist;
    }
  }

  __shared__ float red[THREADS / 64];
  for (int off = 32; off > 0; off >>= 1) acc += __shfl_down(acc, off, 64);
  const int lane = threadIdx.x & 63;
  const int wid = threadIdx.x >> 6;
  if (lane == 0) red[wid] = acc;
  __syncthreads();
  if (threadIdx.x == 0) {
    float ssum = 0.0f;
    for (int w = 0; w < THREADS / 64; ++w) ssum += red[w];
    atomicAdd(out, ssum * (1.0f / (float)(BB * HH * WW)));
  }
}

extern "C" void kernel_launch(void* const* d_in, const int* in_sizes, int n_in,
                              void* d_out, int out_size, void* d_ws, size_t ws_size,
                              hipStream_t stream) {
  const float* logits = (const float*)d_in[0];
  const int* targets = (const int*)d_in[1];
  float* out = (float*)d_out;
  unsigned* mask = (unsigned*)d_ws;       // 294912 B

  void* args[] = {(void*)&logits, (void*)&targets, (void*)&mask, (void*)&out};
  const hipError_t e = hipLaunchCooperativeKernel(
      (void*)fused_kernel, dim3(NBLOCKS), dim3(THREADS), args, 0, stream);
  if (e != hipSuccess) {
    // Fallback: original verified two-kernel path.
    pack_kernel<<<(BB * HH * WW) / (PTHREADS * 8), PTHREADS, 0, stream>>>(targets, mask, out);
    boundary_loss_kernel<<<BB * NBLK, THREADS, 0, stream>>>(logits, mask, out);
  }
}

// Round 2
// 102.938 us; speedup vs baseline: 1.2156x; 1.2156x over previous
//
#include <hip/hip_runtime.h>
#include <math.h>

// BoundaryLoss: out = mean |sigmoid(logits) - gt| * EDT_bg(gt)
// dist==0 exactly at gt==1  ->  |p-t|*dist == p*dist: targets only feed the
// fg bitmask.
// SINGLE dispatch, no grid.sync, no pre-zeroed output:
//   - each block packs its own image's full fg bitmask from targets -> LDS
//     (XCD swizzle pins all 24 stripes of an image to one XCD: L2-served)
//   - Phase 1: clz/ffs exact nearest-fg row distance per column
//   - Phase 2: exact vertical envelope (early exit) + fused sigmoid*dist
//   - blocks publish partials as double-magic-tagged 64b words (atomicExch,
//     device scope); block 0 polls, validates, deterministic-reduces, stores.
//     Poison-safe: a uniform fill can't match two different magics with
//     equal low words. All 384 blocks co-resident (32.3KB LDS, >=2 blk/CU).

#define BB 16
#define HH 384
#define WW 384
#define WPR 12                 // u32 words per row
#define WPRP 13                // padded LDS stride (coprime 32: conflict-free)
#define SW 16                  // stripe width
#define NBLK (WW / SW)         // 24 stripes per image
#define THREADS 512
#define NBLOCKS (BB * NBLK)    // 384
#define BIGD 768
#define WORDS_PER_IMG (HH * WPR)   // 4608
#define MAGA 0x9E3779B9u
#define MAGB 0x85EBCA77u

__global__ __launch_bounds__(THREADS, 2) void boundary_fused(
    const float* __restrict__ logits, const int* __restrict__ gt,
    unsigned long long* __restrict__ ws, float* __restrict__ out) {
  // XCD swizzle: blockIdx%8 == XCD (round-robin dispatch). 2 images per XCD,
  // all 24 stripes of an image on the same XCD -> targets re-read hits L2.
  const int p = blockIdx.x;
  const int xcd = p & 7;
  const int slot = p >> 3;                  // 0..47
  const int sub = (slot >= NBLK) ? 1 : 0;
  const int b = xcd * 2 + sub;              // image 0..15
  const int j0 = (slot - sub * NBLK) * SW;  // stripe origin column
  const float* __restrict__ lg = logits + b * HH * WW;
  const int* __restrict__ gimg = gt + b * HH * WW;

  __shared__ unsigned m_s[HH * WPRP];       // 19968 B
  __shared__ unsigned short g_s[HH * SW];   // 12288 B

  // ---- Phase 0: pack this image's fg bitmask straight into LDS ----
  for (int wi = threadIdx.x; wi < WORDS_PER_IMG; wi += THREADS) {  // 9 iters
    const int4* __restrict__ g4 = (const int4*)(gimg + wi * 32);
    unsigned word = 0;
#pragma unroll
    for (int k = 0; k < 8; ++k) {
      const int4 v = g4[k];
      word |= ((unsigned)(v.x != 0)) << (k * 4);
      word |= ((unsigned)(v.y != 0)) << (k * 4 + 1);
      word |= ((unsigned)(v.z != 0)) << (k * 4 + 2);
      word |= ((unsigned)(v.w != 0)) << (k * 4 + 3);
    }
    const int row = wi / WPR;
    const int w = wi - row * WPR;
    m_s[row * WPRP + w] = word;
  }
  __syncthreads();

  // ---- Phase 1: exact nearest-fg row distance, 4 cols/thread ----
  for (int s = threadIdx.x; s < HH * (SW / 4); s += THREADS) {  // 1536
    const int i = s >> 2;
    const int jj = (s & 3) * 4;
    const int j = j0 + jj;                  // multiple of 4: 4 bits in one word
    const unsigned* __restrict__ mr = m_s + i * WPRP;
    const int w = j >> 5;
    const int bpos = j & 31;                // 0,4,...,28
    const unsigned cur = mr[w];

    int jL = -0x40000;
    if ((cur & (0xFFFFFFFFu >> (31 - bpos))) == 0u) {
      for (int ww = w - 1; ww >= 0; --ww) {
        const unsigned x = mr[ww];
        if (x) { jL = ww * 32 + 31 - __clz(x); break; }
      }
    }
    int jR = 0x40000;
    if ((cur & (0xFFFFFFFFu << (bpos + 3))) == 0u) {
      for (int ww = w + 1; ww < WPR; ++ww) {
        const unsigned x = mr[ww];
        if (x) { jR = ww * 32 + __ffs(x) - 1; break; }
      }
    }
    unsigned short g4[4];
#pragma unroll
    for (int c = 0; c < 4; ++c) {
      const int bc = bpos + c;
      const int jc = j + c;
      const unsigned lm = cur & (0xFFFFFFFFu >> (31 - bc));
      const unsigned rm = cur & (0xFFFFFFFFu << bc);
      const int dl = lm ? (bc - (31 - __clz(lm))) : (jc - jL);
      const int dr = rm ? ((__ffs(rm) - 1) - bc) : (jR - jc);
      g4[c] = (unsigned short)min(min(dl, dr), BIGD);
    }
    ushort4 gv; gv.x = g4[0]; gv.y = g4[1]; gv.z = g4[2]; gv.w = g4[3];
    *(ushort4*)(g_s + i * SW + jj) = gv;
  }
  __syncthreads();

  // ---- Phase 2: exact vertical envelope (early exit r*r >= best) + loss ----
  float acc = 0.0f;
  for (int s = threadIdx.x; s < HH * (SW / 4); s += THREADS) {
    const int i = s >> 2;
    const int jj = (s & 3) * 4;
    const ushort4 gv = *(const ushort4*)(g_s + i * SW + jj);
    const float4 x4 = *(const float4*)(lg + i * WW + j0 + jj);
    const int gg[4] = {gv.x, gv.y, gv.z, gv.w};
    const float xs[4] = {x4.x, x4.y, x4.z, x4.w};
#pragma unroll
    for (int c = 0; c < 4; ++c) {
      int best = gg[c] * gg[c];
      for (int r = 1; r * r < best; ++r) {
        const int im = i - r, ip = i + r;
        if (im >= 0) { const int v = g_s[im * SW + jj + c]; best = min(best, r * r + v * v); }
        if (ip < HH) { const int v = g_s[ip * SW + jj + c]; best = min(best, r * r + v * v); }
      }
      const float dist = __builtin_amdgcn_sqrtf((float)best);     // rel ~1e-7
      const float p2 = __builtin_amdgcn_rcpf(1.0f + __expf(-xs[c])); // ~2.5e-7
      acc += p2 * dist;                       // == |p-t|*dist (dist=0 at fg)
    }
  }

  // ---- Block reduction -> publish tagged partial ----
  __shared__ float red[THREADS / 64];
  for (int off = 32; off > 0; off >>= 1) acc += __shfl_down(acc, off, 64);
  const int lane = threadIdx.x & 63;
  const int wid = threadIdx.x >> 6;
  if (lane == 0) red[wid] = acc;
  __syncthreads();
  if (threadIdx.x == 0) {
    float ssum = 0.0f;
    for (int w = 0; w < THREADS / 64; ++w) ssum += red[w];
    const unsigned vb = __float_as_uint(ssum);
    // self-validating {value, magic} words; single RMW each -> no fence needed
    atomicExch(ws + 2 * p,     (((unsigned long long)MAGA) << 32) | vb);
    atomicExch(ws + 2 * p + 1, (((unsigned long long)MAGB) << 32) | vb);
  }

  // ---- Consumer: block 0 polls all partials, deterministic final reduce ----
  if (p == 0) {
    const int t = threadIdx.x;
    float v = 0.0f;
    if (t < NBLOCKS) {
      for (;;) {
        const unsigned long long a = atomicAdd(ws + 2 * t, 0ULL);     // dev-scope load
        const unsigned long long c = atomicAdd(ws + 2 * t + 1, 0ULL);
        if ((unsigned)(a >> 32) == MAGA && (unsigned)(c >> 32) == MAGB &&
            (unsigned)a == (unsigned)c) {
          v = __uint_as_float((unsigned)a);
          break;
        }
        __builtin_amdgcn_s_sleep(8);
      }
    }
    for (int off = 32; off > 0; off >>= 1) v += __shfl_down(v, off, 64);
    __syncthreads();                        // red[] free for reuse
    if (lane == 0) red[wid] = v;
    __syncthreads();
    if (t == 0) {
      float s = 0.0f;
      for (int w = 0; w < THREADS / 64; ++w) s += red[w];
      out[0] = s * (1.0f / (float)(BB * HH * WW));
    }
  }
}

extern "C" void kernel_launch(void* const* d_in, const int* in_sizes, int n_in,
                              void* d_out, int out_size, void* d_ws, size_t ws_size,
                              hipStream_t stream) {
  const float* logits = (const float*)d_in[0];
  const int* targets = (const int*)d_in[1];
  float* out = (float*)d_out;
  unsigned long long* ws = (unsigned long long*)d_ws;   // 384*16 B used

  boundary_fused<<<NBLOCKS, THREADS, 0, stream>>>(logits, targets, ws, out);
}

// Round 3
// 79.509 us; speedup vs baseline: 1.5738x; 1.2947x over previous
//
#include <hip/hip_runtime.h>
#include <math.h>

// BoundaryLoss: out = mean |sigmoid(logits) - gt| * EDT_bg(gt)
// dist==0 exactly at gt==1  ->  |p-t|*dist == p*dist: targets only feed the
// fg bitmask.
// SINGLE dispatch, no grid.sync, no pre-zeroed output, NO redundant packing:
//   - producer role: each block packs its own 16-row band of its image's fg
//     bitmask (192 words) and publishes tagged 64b words {MAGIC|word} via
//     atomicExch (tag+data same word -> no fence needed, poison-safe).
//   - consumer role: each block assembles the full image mask from L2 by
//     polling the 24 producer bands of its image (device-scope atomic loads).
//     All 384 blocks co-resident (32.3KB LDS, 512 thr -> 4 blk/CU cap) and
//     an image's producers == its consumers -> deadlock-free.
//   - Phase 1: clz/ffs exact nearest-fg row distance per column
//   - Phase 2: exact vertical envelope (early exit) + fused sigmoid*dist,
//     logits prefetched at kernel start (issue-early / use-late).
//   - partials published tagged; block 0 polls, deterministic-reduces, stores.

#define BB 16
#define HH 384
#define WW 384
#define WPR 12                 // u32 words per row
#define WPRP 13                // padded LDS stride (coprime 32: conflict-free)
#define SW 16                  // stripe width
#define NBLK (WW / SW)         // 24 stripes per image == 24 row-bands
#define RPB (HH / NBLK)        // 16 rows packed per producer block
#define THREADS 512
#define NBLOCKS (BB * NBLK)    // 384
#define BIGD 768
#define WORDS_PER_IMG (HH * WPR)       // 4608 = 512*9
#define WPB (RPB * WPR)                // 192 words produced per block
#define PART_BASE (BB * WORDS_PER_IMG) // 73728 (in 8B slots)
#define MAGA 0x9E3779B9u
#define TAG64 (((unsigned long long)MAGA) << 32)

__global__ __launch_bounds__(THREADS, 2) void boundary_fused(
    const float* __restrict__ logits, const int* __restrict__ gt,
    unsigned long long* ws, float* __restrict__ out) {
  // XCD swizzle: blockIdx%8 == XCD (round-robin dispatch). 2 images per XCD,
  // all 24 blocks of an image on the same XCD -> mask handoff stays in L2.
  const int p = blockIdx.x;
  const int xcd = p & 7;
  const int slot = p >> 3;                  // 0..47
  const int sub = (slot >= NBLK) ? 1 : 0;
  const int b = xcd * 2 + sub;              // image 0..15
  const int st = slot - sub * NBLK;         // stripe / band index 0..23
  const int j0 = st * SW;                   // stripe origin column
  const int r0 = st * RPB;                  // producer band origin row
  const float* __restrict__ lg = logits + b * HH * WW;
  const int* __restrict__ gimg = gt + b * HH * WW;
  unsigned long long* mimg = ws + (size_t)b * WORDS_PER_IMG;

  __shared__ unsigned m_s[HH * WPRP];       // 19968 B
  __shared__ unsigned short g_s[HH * SW];   // 12288 B
  __shared__ float red[THREADS / 64];

  // ---- Prefetch logits stripe into registers (consumed in Phase 2) ----
  float4 xf[3];
#pragma unroll
  for (int t = 0; t < 3; ++t) {
    const int s = threadIdx.x + t * THREADS;        // < 1536
    const int i = s >> 2;
    const int jj = (s & 3) * 4;
    xf[t] = *(const float4*)(lg + i * WW + j0 + jj);
  }

  // ---- Producer: pack own 16-row band (192 words), publish tagged ----
  if (threadIdx.x < WPB) {
    const int q = threadIdx.x;              // 0..191
    const int rr = q / WPR;                 // 0..15
    const int w = q - rr * WPR;             // 0..11
    const int r = r0 + rr;
    const int4* __restrict__ g4 = (const int4*)(gimg + r * WW + w * 32);
    unsigned word = 0;
#pragma unroll
    for (int k = 0; k < 8; ++k) {
      const int4 v = g4[k];
      word |= ((unsigned)(v.x != 0)) << (k * 4);
      word |= ((unsigned)(v.y != 0)) << (k * 4 + 1);
      word |= ((unsigned)(v.z != 0)) << (k * 4 + 2);
      word |= ((unsigned)(v.w != 0)) << (k * 4 + 3);
    }
    atomicExch(mimg + (r * WPR + w), TAG64 | (unsigned long long)word);
  }

  // ---- Consumer: assemble full image mask from tagged words (L2) ----
#pragma unroll
  for (int t = 0; t < 9; ++t) {             // 4608 = 512*9
    const int wi = threadIdx.x + t * THREADS;
    unsigned long long v =
        __hip_atomic_load(mimg + wi, __ATOMIC_RELAXED, __HIP_MEMORY_SCOPE_AGENT);
    while ((unsigned)(v >> 32) != MAGA) {
      __builtin_amdgcn_s_sleep(2);
      v = __hip_atomic_load(mimg + wi, __ATOMIC_RELAXED, __HIP_MEMORY_SCOPE_AGENT);
    }
    const int row = wi / WPR;
    const int w = wi - row * WPR;
    m_s[row * WPRP + w] = (unsigned)v;
  }
  __syncthreads();

  // ---- Phase 1: exact nearest-fg row distance, 4 cols/thread ----
#pragma unroll
  for (int t = 0; t < 3; ++t) {             // 1536 = 512*3
    const int s = threadIdx.x + t * THREADS;
    const int i = s >> 2;
    const int jj = (s & 3) * 4;
    const int j = j0 + jj;                  // multiple of 4: 4 bits in one word
    const unsigned* __restrict__ mr = m_s + i * WPRP;
    const int w = j >> 5;
    const int bpos = j & 31;                // 0,4,...,28
    const unsigned cur = mr[w];

    int jL = -0x40000;
    if ((cur & (0xFFFFFFFFu >> (31 - bpos))) == 0u) {
      for (int ww = w - 1; ww >= 0; --ww) {
        const unsigned x = mr[ww];
        if (x) { jL = ww * 32 + 31 - __clz(x); break; }
      }
    }
    int jR = 0x40000;
    if ((cur & (0xFFFFFFFFu << (bpos + 3))) == 0u) {
      for (int ww = w + 1; ww < WPR; ++ww) {
        const unsigned x = mr[ww];
        if (x) { jR = ww * 32 + __ffs(x) - 1; break; }
      }
    }
    unsigned short g4[4];
#pragma unroll
    for (int c = 0; c < 4; ++c) {
      const int bc = bpos + c;
      const int jc = j + c;
      const unsigned lm = cur & (0xFFFFFFFFu >> (31 - bc));
      const unsigned rm = cur & (0xFFFFFFFFu << bc);
      const int dl = lm ? (bc - (31 - __clz(lm))) : (jc - jL);
      const int dr = rm ? ((__ffs(rm) - 1) - bc) : (jR - jc);
      g4[c] = (unsigned short)min(min(dl, dr), BIGD);
    }
    ushort4 gv; gv.x = g4[0]; gv.y = g4[1]; gv.z = g4[2]; gv.w = g4[3];
    *(ushort4*)(g_s + i * SW + jj) = gv;
  }
  __syncthreads();

  // ---- Phase 2: exact vertical envelope (early exit r*r >= best) + loss ----
  float acc = 0.0f;
#pragma unroll
  for (int t = 0; t < 3; ++t) {
    const int s = threadIdx.x + t * THREADS;
    const int i = s >> 2;
    const int jj = (s & 3) * 4;
    const ushort4 gv = *(const ushort4*)(g_s + i * SW + jj);
    const float4 x4 = xf[t];
    const int gg[4] = {gv.x, gv.y, gv.z, gv.w};
    const float xs[4] = {x4.x, x4.y, x4.z, x4.w};
#pragma unroll
    for (int c = 0; c < 4; ++c) {
      int best = gg[c] * gg[c];
      for (int r = 1; r * r < best; ++r) {
        const int im = i - r, ip = i + r;
        if (im >= 0) { const int v = g_s[im * SW + jj + c]; best = min(best, r * r + v * v); }
        if (ip < HH) { const int v = g_s[ip * SW + jj + c]; best = min(best, r * r + v * v); }
      }
      const float dist = __builtin_amdgcn_sqrtf((float)best);     // rel ~1e-7
      const float p2 = __builtin_amdgcn_rcpf(1.0f + __expf(-xs[c])); // ~2.5e-7
      acc += p2 * dist;                       // == |p-t|*dist (dist=0 at fg)
    }
  }

  // ---- Block reduction -> publish tagged partial ----
  for (int off = 32; off > 0; off >>= 1) acc += __shfl_down(acc, off, 64);
  const int lane = threadIdx.x & 63;
  const int wid = threadIdx.x >> 6;
  if (lane == 0) red[wid] = acc;
  __syncthreads();
  if (threadIdx.x == 0) {
    float ssum = 0.0f;
    for (int w = 0; w < THREADS / 64; ++w) ssum += red[w];
    atomicExch(ws + PART_BASE + p,
               TAG64 | (unsigned long long)__float_as_uint(ssum));
  }

  // ---- Consumer: block 0 polls all partials, deterministic final reduce ----
  if (p == 0) {
    const int t = threadIdx.x;
    float v = 0.0f;
    if (t < NBLOCKS) {
      unsigned long long a = __hip_atomic_load(ws + PART_BASE + t,
                                               __ATOMIC_RELAXED,
                                               __HIP_MEMORY_SCOPE_AGENT);
      while ((unsigned)(a >> 32) != MAGA) {
        __builtin_amdgcn_s_sleep(2);
        a = __hip_atomic_load(ws + PART_BASE + t, __ATOMIC_RELAXED,
                              __HIP_MEMORY_SCOPE_AGENT);
      }
      v = __uint_as_float((unsigned)a);
    }
    for (int off = 32; off > 0; off >>= 1) v += __shfl_down(v, off, 64);
    __syncthreads();                        // red[] free for reuse
    if (lane == 0) red[wid] = v;
    __syncthreads();
    if (t == 0) {
      float s = 0.0f;
      for (int w = 0; w < THREADS / 64; ++w) s += red[w];
      out[0] = s * (1.0f / (float)(BB * HH * WW));
    }
  }
}

extern "C" void kernel_launch(void* const* d_in, const int* in_sizes, int n_in,
                              void* d_out, int out_size, void* d_ws, size_t ws_size,
                              hipStream_t stream) {
  const float* logits = (const float*)d_in[0];
  const int* targets = (const int*)d_in[1];
  float* out = (float*)d_out;
  unsigned long long* ws = (unsigned long long*)d_ws;  // 592,896 B used

  boundary_fused<<<NBLOCKS, THREADS, 0, stream>>>(logits, targets, ws, out);
}